// Round 9
// baseline (243.704 us; speedup 1.0000x reference)
//
#include <hip/hip_runtime.h>

// ---------------- constants (B=8,S=8192 -> N=65536, D=512, E=209) ------------
#define DK 512         // feature dim
#define TMB 128        // tokens per block (4 waves x 32 tokens)
#define NSTEP 16       // K steps of 32
#define NPANEL 14      // expert panels of 16 -> EPAD
#define EPAD 224
#define WFRAG_ELEMS (EPAD * DK)   // 114688 bf16 per array

typedef __attribute__((ext_vector_type(8))) short bf16x8;   // 8 bf16 = 4 VGPR
typedef __attribute__((ext_vector_type(4))) float f32x4;

__device__ __forceinline__ unsigned short f2b(float f) {   // f32 -> bf16 RNE
    unsigned u = __float_as_uint(f);
    return (unsigned short)((u + 0x7fffu + ((u >> 16) & 1u)) >> 16);
}
__device__ __forceinline__ float b2f(unsigned short h) {
    return __uint_as_float((unsigned)h << 16);
}
// RNE split (prep only)
__device__ __forceinline__ void split4(float4 v, ushort4& h, ushort4& lo) {
    h.x = f2b(v.x); h.y = f2b(v.y); h.z = f2b(v.z); h.w = f2b(v.w);
    lo.x = f2b(v.x - b2f(h.x)); lo.y = f2b(v.y - b2f(h.y));
    lo.z = f2b(v.z - b2f(h.z)); lo.w = f2b(v.w - b2f(h.w));
}
// 8 consecutive f32 -> hi (trunc, residual exact) + lo (RNE) bf16x8
__device__ __forceinline__ void pack8(float4 a, float4 b, bf16x8& h, bf16x8& lo) {
    float v[8] = {a.x, a.y, a.z, a.w, b.x, b.y, b.z, b.w};
    #pragma unroll
    for (int j = 0; j < 8; ++j) {
        unsigned u = __float_as_uint(v[j]);
        h[j]  = (short)(u >> 16);
        lo[j] = (short)f2b(v[j] - __uint_as_float(u & 0xffff0000u));
    }
}

// ---------------------------------------------------------------- init -------
extern "C" __global__ void moe_init(float* hist, float* probsum, int* cnt) {
    int t = threadIdx.x;
    if (t < EPAD) { hist[t] = 0.f; probsum[t] = 0.f; }
    if (t == 0) *cnt = 0;
}

// ---------------------------------------------------------------- prep -------
// One-time: w [E][DK] f32 -> fragment-major bf16 hi/lo arrays.
// idx = ((kk*14+p)*64 + l)*8 + j  holds  w[p*16+(l&15)][kk*32+(l>>4)*8+j].
extern "C" __global__ void __launch_bounds__(256)
moe_prep(const float* __restrict__ w,
         unsigned short* __restrict__ wHi,
         unsigned short* __restrict__ wLo, int E)
{
    int g = blockIdx.x * 256 + threadIdx.x;      // 0..14335
    int l  = g & 63;
    int pc = g >> 6;                              // kk*14 + p
    int kk = pc / NPANEL;
    int p  = pc - kk * NPANEL;
    int e  = p * 16 + (l & 15);
    int k0 = kk * 32 + (l >> 4) * 8;
    float4 v0 = make_float4(0.f,0.f,0.f,0.f), v1 = v0;
    if (e < E) {
        v0 = *(const float4*)(w + (size_t)e * DK + k0);
        v1 = *(const float4*)(w + (size_t)e * DK + k0 + 4);
    }
    ushort4 h0, l0, h1, l1;
    split4(v0, h0, l0); split4(v1, h1, l1);
    size_t off = (size_t)g * 8;
    *(ushort4*)(wHi + off)     = h0;
    *(ushort4*)(wHi + off + 4) = h1;
    *(ushort4*)(wLo + off)     = l0;
    *(ushort4*)(wLo + off + 4) = l1;
}

// ---------------------------------------------------------------- main -------
// Barrier-free, LDS-free GEMM. Wave wm owns 32 tokens x 224 experts
// (acc 28 f32x4). A frags loaded DIRECTLY from global (lane l: rows
// tok0+{le,16+le}, k (lg*8..+7)) and split in-register; doubles as the
// x_flat copy. B frags from frag-major wHi/wLo (L2-resident). Softmax
// fully in-register via 16-lane butterflies (C layout: col=lane&15).
extern "C" __global__ void __launch_bounds__(256, 2)
moe_main(const float* __restrict__ x,
         const unsigned short* __restrict__ wHi,
         const unsigned short* __restrict__ wLo,
         float* __restrict__ out,
         float* __restrict__ hist,
         float* __restrict__ probsum_g,
         int* __restrict__ flag_cnt,
         int* __restrict__ flag_list,
         int flag_cap, int N, int E)
{
    __shared__ float ps_l[EPAD];

    const int t  = threadIdx.x;
    const int l  = t & 63;
    const int wm = t >> 6;
    const int le = l & 15;                 // expert-in-panel / token row low
    const int lg = l >> 4;                 // k-slice group / row group
    const int tok0 = blockIdx.x * TMB + wm * 32;

    if (t < EPAD) ps_l[t] = 0.f;

    const float* xr0 = x + (size_t)(tok0 + le) * DK + lg * 8;
    const float* xr1 = xr0 + (size_t)16 * DK;
    float* ow0 = out + (size_t)(tok0 + le) * DK + lg * 8;
    float* ow1 = ow0 + (size_t)16 * DK;

    f32x4 acc[2][NPANEL];
    #pragma unroll
    for (int mi = 0; mi < 2; ++mi)
        #pragma unroll
        for (int pp = 0; pp < NPANEL; ++pp)
            acc[mi][pp] = (f32x4){0.f, 0.f, 0.f, 0.f};

    #pragma unroll 2
    for (int kk = 0; kk < NSTEP; ++kk) {
        // ---- A: 4 float4 global loads (rows le, le+16), doubles as copy ----
        float4 a00 = *(const float4*)(xr0 + kk * 32);
        float4 a01 = *(const float4*)(xr0 + kk * 32 + 4);
        float4 a10 = *(const float4*)(xr1 + kk * 32);
        float4 a11 = *(const float4*)(xr1 + kk * 32 + 4);
        *(float4*)(ow0 + kk * 32)     = a00;
        *(float4*)(ow0 + kk * 32 + 4) = a01;
        *(float4*)(ow1 + kk * 32)     = a10;
        *(float4*)(ow1 + kk * 32 + 4) = a11;
        bf16x8 ah0, al0, ah1, al1;
        pack8(a00, a01, ah0, al0);
        pack8(a10, a11, ah1, al1);
        // ---- B frags straight from global (L2); 84 MFMA ----
        #pragma unroll
        for (int pp = 0; pp < NPANEL; ++pp) {
            size_t boff = ((size_t)(kk * NPANEL + pp) * 64 + l) * 8;
            bf16x8 bh = *(const bf16x8*)(wHi + boff);
            bf16x8 bl = *(const bf16x8*)(wLo + boff);
            acc[0][pp] = __builtin_amdgcn_mfma_f32_16x16x32_bf16(ah0, bh, acc[0][pp], 0, 0, 0);
            acc[0][pp] = __builtin_amdgcn_mfma_f32_16x16x32_bf16(ah0, bl, acc[0][pp], 0, 0, 0);
            acc[0][pp] = __builtin_amdgcn_mfma_f32_16x16x32_bf16(al0, bh, acc[0][pp], 0, 0, 0);
            acc[1][pp] = __builtin_amdgcn_mfma_f32_16x16x32_bf16(ah1, bh, acc[1][pp], 0, 0, 0);
            acc[1][pp] = __builtin_amdgcn_mfma_f32_16x16x32_bf16(ah1, bl, acc[1][pp], 0, 0, 0);
            acc[1][pp] = __builtin_amdgcn_mfma_f32_16x16x32_bf16(al1, bh, acc[1][pp], 0, 0, 0);
        }
    }

    // -------- phase 2: in-register softmax (C layout: col=le, row=lg*4+rg) --
    float m1r[8], svr[8];
    #pragma unroll
    for (int mi = 0; mi < 2; ++mi) {
        #pragma unroll
        for (int rg = 0; rg < 4; ++rg) {
            const int r8 = mi * 4 + rg;
            float m1 = -1e30f, m2 = -1e30f; int i1 = 0x7fff;
            #pragma unroll
            for (int pp = 0; pp < NPANEL; ++pp) {
                int e = pp * 16 + le;
                float v = (e < E) ? acc[mi][pp][rg] : -1e30f;
                if (v > m1) { m2 = m1; m1 = v; i1 = e; }
                else if (v > m2) { m2 = v; }
            }
            #pragma unroll
            for (int mask = 1; mask < 16; mask <<= 1) {   // reduce over experts
                float om1 = __shfl_xor(m1, mask);
                float om2 = __shfl_xor(m2, mask);
                int   oi1 = __shfl_xor(i1, mask);
                if (om1 > m1 || (om1 == m1 && oi1 < i1)) {
                    m2 = fmaxf(m1, om2); m1 = om1; i1 = oi1;
                } else {
                    m2 = fmaxf(m2, om1);
                }
            }
            float s = 0.f;
            #pragma unroll
            for (int pp = 0; pp < NPANEL; ++pp) {
                int e = pp * 16 + le;
                float v = (e < E) ? acc[mi][pp][rg] : -1e30f;
                s += __expf(v - m1);                       // invalid -> 0
            }
            #pragma unroll
            for (int mask = 1; mask < 16; mask <<= 1) s += __shfl_xor(s, mask);
            float sinv = 1.0f / s;
            m1r[r8] = m1; svr[r8] = sinv;
            if (le == 0) {                                 // writer lane
                int tok = tok0 + mi * 16 + lg * 4 + rg;
                out[(size_t)N * DK + tok]     = sinv;      // max prob
                out[(size_t)N * DK + N + tok] = (float)i1; // expert index
                atomicAdd(&hist[i1], 1.0f);
                if (m1 - m2 < 1e-4f) {                     // ambiguous argmax
                    int pos = atomicAdd(flag_cnt, 1);
                    if (pos < flag_cap) flag_list[pos] = tok;
                }
            }
        }
    }

    // -------- per-expert prob sums: reduce rows in-reg, then lanes 16/32 ----
    float ps[NPANEL];
    #pragma unroll
    for (int pp = 0; pp < NPANEL; ++pp) {
        float sum = 0.f;
        #pragma unroll
        for (int mi = 0; mi < 2; ++mi)
            #pragma unroll
            for (int rg = 0; rg < 4; ++rg) {
                int e = pp * 16 + le;
                float v = (e < E) ? acc[mi][pp][rg] : -1e30f;
                sum += __expf(v - m1r[mi * 4 + rg]) * svr[mi * 4 + rg];
            }
        sum += __shfl_xor(sum, 16);
        sum += __shfl_xor(sum, 32);
        ps[pp] = sum;
    }
    __syncthreads();                                       // ps_l init visible
    if (lg == 0) {
        #pragma unroll
        for (int pp = 0; pp < NPANEL; ++pp) {
            int e = pp * 16 + le;
            if (e < E) atomicAdd(&ps_l[e], ps[pp]);
        }
    }
    __syncthreads();
    if (t < E) atomicAdd(&probsum_g[t], ps_l[t]);
}

// ------------------------------------------------------------- refine --------
// f64 recompute (original f32 w) for tokens with f32 top-2 gap < tau.
extern "C" __global__ void __launch_bounds__(256)
moe_refine(const float* __restrict__ x,
           const float* __restrict__ w,
           float* __restrict__ hist,
           const int* __restrict__ flag_cnt,
           const int* __restrict__ flag_list,
           int flag_cap,
           float* __restrict__ out,
           int N, int E)
{
    __shared__ float  xsh[DK];
    __shared__ double rv[256];
    __shared__ int    ri[256];
    int nf = *flag_cnt; if (nf > flag_cap) nf = flag_cap;
    const int tid = threadIdx.x;

    for (int li = blockIdx.x; li < nf; li += gridDim.x) {
        int tok = flag_list[li];
        for (int k = tid; k < DK; k += 256) xsh[k] = x[(size_t)tok * DK + k];
        __syncthreads();
        double a = -1e300;
        if (tid < E) {
            const float* wr = w + (size_t)tid * DK;
            double a0 = 0, a1 = 0, a2 = 0, a3 = 0;
            for (int k = 0; k < DK; k += 4) {
                a0 += (double)xsh[k]     * (double)wr[k];
                a1 += (double)xsh[k + 1] * (double)wr[k + 1];
                a2 += (double)xsh[k + 2] * (double)wr[k + 2];
                a3 += (double)xsh[k + 3] * (double)wr[k + 3];
            }
            a = (a0 + a1) + (a2 + a3);
        }
        rv[tid] = a; ri[tid] = tid;
        __syncthreads();
        for (int s = 128; s > 0; s >>= 1) {
            if (tid < s) {
                double vb = rv[tid + s]; int ib = ri[tid + s];
                double va = rv[tid];     int ia = ri[tid];
                if (vb > va || (vb == va && ib < ia)) { rv[tid] = vb; ri[tid] = ib; }
            }
            __syncthreads();
        }
        if (tid == 0) {
            int newi = ri[0];
            int oldi = (int)out[(size_t)N * DK + N + tok];
            if (newi != oldi) {
                atomicAdd(&hist[oldi], -1.0f);
                atomicAdd(&hist[newi],  1.0f);
                out[(size_t)N * DK + N + tok] = (float)newi;
            }
        }
        __syncthreads();
    }
}

// ------------------------------------------------------------ finalize -------
extern "C" __global__ void __launch_bounds__(256)
moe_final(const float* __restrict__ hist,
          const float* __restrict__ probsum,
          const float* __restrict__ ec_in,
          const float* __restrict__ gps_in,
          float* __restrict__ out,
          int N, int E)
{
    __shared__ double red[256];
    int t = threadIdx.x;
    double p = 0.0;
    if (t < E) p = (double)hist[t] * (double)probsum[t];
    red[t] = p;
    __syncthreads();
    for (int s = 128; s > 0; s >>= 1) {
        if (t < s) red[t] += red[t + s];
        __syncthreads();
    }
    size_t base = (size_t)N * DK + 2 * (size_t)N;
    if (t == 0) {
        double loss = (double)E * red[0] / ((double)N * (double)N);
        out[base] = (float)loss;
    }
    if (t < E) {
        out[base + 1 + t]     = 0.9f * ec_in[t]  + 0.1f * hist[t];
        out[base + 1 + E + t] = 0.9f * gps_in[t] + 0.1f * probsum[t];
    }
}

// ------------------------------------------------------------- launch --------
extern "C" void kernel_launch(void* const* d_in, const int* in_sizes, int n_in,
                              void* d_out, int out_size, void* d_ws, size_t ws_size,
                              hipStream_t stream)
{
    const float* x   = (const float*)d_in[0];
    const float* w   = (const float*)d_in[1];
    const float* ec  = (const float*)d_in[2];
    const float* gps = (const float*)d_in[3];
    float* out = (float*)d_out;

    int E = in_sizes[2];              // 209
    int N = in_sizes[0] / DK;         // 65536

    unsigned short* wHi = (unsigned short*)d_ws;
    unsigned short* wLo = wHi + WFRAG_ELEMS;
    float* hist    = (float*)(wLo + WFRAG_ELEMS);
    float* probsum = hist + EPAD;
    int*   cnt     = (int*)(probsum + EPAD);
    int*   list    = cnt + 1;
    long long used = 2LL * WFRAG_ELEMS * 2 + 4LL * (2 * EPAD + 1);
    long long cap_ll = ((long long)ws_size - used) / 4;
    int cap = cap_ll < 0 ? 0 : (cap_ll > 65536 ? 65536 : (int)cap_ll);

    moe_prep  <<<56,      256, 0, stream>>>(w, wHi, wLo, E);
    moe_init  <<<1,       256, 0, stream>>>(hist, probsum, cnt);
    moe_main  <<<N / TMB, 256, 0, stream>>>(x, wHi, wLo, out, hist, probsum, cnt, list, cap, N, E);
    moe_refine<<<256,     256, 0, stream>>>(x, w, hist, cnt, list, cap, out, N, E);
    moe_final <<<1,       256, 0, stream>>>(hist, probsum, ec, gps, out, N, E);
}